// Round 6
// baseline (30534.409 us; speedup 1.0000x reference)
//
#include <hip/hip_runtime.h>
#include <hip/hip_bf16.h>
#include <hip/hip_fp16.h>

// ---------------------------------------------------------------------------
// POSTagger: char-CNN -> concat(word emb) -> xg GEMM -> sequential LSTM (the
// bottleneck, single workgroup / one CU) -> dense + log_softmax.
// Sizes: S=4096, LC=16, CDIM=10, F=32, WDIM=250, H=250, 4H=1000,
//        K=F+WDIM=282, TAGS=50.
//
// LSTM (round 5, resubmitted unchanged after broker timeout):
// 512 threads / 8 waves, thread owns rows 2tid,2tid+1.
//  - pairs 0..95 of each row in VGPRs (48 uint4 = 192 regs), pinned by
//    amdgpu_waves_per_eu(2,2) + opaque asm (round-4 failure: allocator
//    targeted 4 waves/EU and evicted the weights -> 512KB/step L2 traffic).
//  - pairs 96..127 stream from LDS (128 KB) at the BW floor each step.
//  - h_{t-1} broadcast from LDS (128 packed f16 pairs, same-address reads).
// ---------------------------------------------------------------------------

typedef _Float16 h2 __attribute__((ext_vector_type(2)));

__device__ __forceinline__ float dot2(unsigned int w, unsigned int h, float acc) {
#if __has_builtin(__builtin_amdgcn_fdot2)
    return __builtin_amdgcn_fdot2(__builtin_bit_cast(h2, w),
                                  __builtin_bit_cast(h2, h), acc, false);
#else
    h2 a = __builtin_bit_cast(h2, w), b = __builtin_bit_cast(h2, h);
    return acc + (float)a[0] * (float)b[0] + (float)a[1] * (float)b[1];
#endif
}

// ---------------------------------------------------------------------------
// K0: pack W_hh (f16) into K3's layout. 64 groups x 512 threads of uint4:
//   group gu<48:  m=gu/24, u=gu%24 -> pairs 4u..4u+3   of row 2tid+m (regs)
//   group 48+gt:  m=gt>>3, c=gt&7  -> pairs 96+4c..+3  of row 2tid+m (LDS)
// pair p holds f16(W[row][2p]), f16(W[row][2p+1]); zero when 2p>=250.
// Rows clamp at 998/999 for tid>=500 (values unused).
// ---------------------------------------------------------------------------
__global__ void prep_kernel(const float* __restrict__ whh,  // [1000][250]
                            uint4* __restrict__ wpackF) {
    int id = blockIdx.x * 256 + threadIdx.x;      // 0..32767
    if (id >= 32768) return;
    int tid = id & 511;
    int gu = id >> 9;            // 0..63
    int m, p0;
    if (gu < 48) { m = gu / 24; int u = gu % 24; p0 = 4 * u; }
    else         { int gt = gu - 48; m = gt >> 3; p0 = 96 + 4 * (gt & 7); }
    int row = 2 * tid + m;
    if (row > 999) row = 998 + m;
    unsigned ww[4];
#pragma unroll
    for (int c = 0; c < 4; ++c) {
        int p = p0 + c;
        float e0 = (2 * p < 250)     ? whh[row * 250 + 2 * p]     : 0.0f;
        float e1 = (2 * p + 1 < 250) ? whh[row * 250 + 2 * p + 1] : 0.0f;
        h2 hp; hp[0] = (_Float16)e0; hp[1] = (_Float16)e1;
        ww[c] = __builtin_bit_cast(unsigned, hp);
    }
    uint4 v; v.x = ww[0]; v.y = ww[1]; v.z = ww[2]; v.w = ww[3];
    wpackF[(gu << 9) + tid] = v;
}

// ---------------------------------------------------------------------------
// K1: xT[282][4096]: rows 0..31 = char-CNN features^T (conv3 pad1 + bias +
// max over time), rows 32..281 = gathered word embeddings^T. 64 words/block.
// ---------------------------------------------------------------------------
__global__ __launch_bounds__(256) void build_xt(
    const int* __restrict__ ci, const int* __restrict__ wi,
    const float* __restrict__ cemb, const float* __restrict__ wemb,
    const float* __restrict__ convw, const float* __restrict__ convb,
    float* __restrict__ xT) {
    __shared__ float ce[64][16][10];
    __shared__ float cw[32][30];
    __shared__ float cb[32];
    __shared__ int widx[64];
    const int tid = threadIdx.x;
    const int w0 = blockIdx.x * 64;

    for (int i = tid; i < 960; i += 256) cw[i / 30][i % 30] = convw[i];
    if (tid < 32) cb[tid] = convb[tid];
    if (tid < 64) widx[tid] = wi[w0 + tid];
    for (int i = tid; i < 1024; i += 256) {
        int w = i >> 4, lc = i & 15;
        int idx = ci[(w0 + w) * 16 + lc];
#pragma unroll
        for (int c = 0; c < 10; ++c) ce[w][lc][c] = cemb[idx * 10 + c];
    }
    __syncthreads();

    for (int i = tid; i < 2048; i += 256) {
        int w = i >> 5, f = i & 31;
        float mx = -1e30f;
        for (int t = 0; t < 16; ++t) {
            float s = cb[f];
#pragma unroll
            for (int dt = 0; dt < 3; ++dt) {
                int tt = t + dt - 1;
                if (tt >= 0 && tt < 16) {
#pragma unroll
                    for (int c = 0; c < 10; ++c)
                        s += ce[w][tt][c] * cw[f][c * 3 + dt];
                }
            }
            mx = fmaxf(mx, s);
        }
        xT[f * 4096 + w0 + w] = mx;
    }
    for (int i = tid; i < 64 * 250; i += 256) {
        int w = i & 63, jj = i >> 6;
        xT[(32 + jj) * 4096 + w0 + w] = wemb[(long)widx[w] * 250 + jj];
    }
}

// ---------------------------------------------------------------------------
// K2: xg[4096][1000] = x @ W_ih^T + (b_ih + b_hh).
// ---------------------------------------------------------------------------
__global__ __launch_bounds__(256) void xg_gemm(
    const float* __restrict__ wih,  // [1000][282]
    const float* __restrict__ xT,   // [282][4096]
    const float* __restrict__ bih, const float* __restrict__ bhh,
    float* __restrict__ xg) {       // [4096][1000]
    const int g = blockIdx.y * 256 + threadIdx.x;
    const int gg = (g < 1000) ? g : 999;
    const int w0 = blockIdx.x * 16;
    float acc[16];
#pragma unroll
    for (int i = 0; i < 16; ++i) acc[i] = 0.0f;
    const float* wrow = wih + gg * 282;
    for (int k = 0; k < 282; ++k) {
        float wv = wrow[k];
        const float* xrow = xT + k * 4096 + w0;
#pragma unroll
        for (int i = 0; i < 16; ++i) acc[i] = fmaf(wv, xrow[i], acc[i]);
    }
    if (g < 1000) {
        float b = bih[g] + bhh[g];
#pragma unroll
        for (int i = 0; i < 16; ++i) xg[(w0 + i) * 1000 + g] = acc[i] + b;
    }
}

// ---------------------------------------------------------------------------
// K3: sequential LSTM. One block, 512 threads (8 waves), one CU.
// Gate rows: i=0..249, f=250..499, g=500..749 (tanh), o=750..999.
// ---------------------------------------------------------------------------
#define DOT4(ACC, W, H)                                                     \
    ACC = dot2((W).x, (H).x, ACC); ACC = dot2((W).y, (H).y, ACC);           \
    ACC = dot2((W).z, (H).z, ACC); ACC = dot2((W).w, (H).w, ACC);

__global__ __launch_bounds__(512)
__attribute__((amdgpu_waves_per_eu(2, 2)))
void lstm_scan(
    const uint4* __restrict__ wpackF,  // [64][512]
    const float* __restrict__ xg,      // [4096][1000]
    float* __restrict__ hsf32) {       // [4096][250]
    __shared__ uint4 lds_wt[16 * 512];  // 128 KB: tail weights [m*8+c][tid]
    __shared__ unsigned lds_h[128];     // h_{t-1} as packed f16 pairs
    __shared__ float lds_gates[1000];

    const int tid = threadIdx.x;
    const bool act_on = (tid < 500);
    const int row0 = act_on ? 2 * tid : 996;       // clamped for safe loads
    const bool isg = (tid >= 250) & (tid < 375);   // rows 500..749 -> tanh

    // pairs 0..95 of both rows -> 48 uint4 = 192 VGPRs, pinned resident
    uint4 wq[2][24];
#pragma unroll
    for (int m = 0; m < 2; ++m)
#pragma unroll
        for (int u = 0; u < 24; ++u)
            wq[m][u] = wpackF[((m * 24 + u) << 9) + tid];
#pragma unroll
    for (int m = 0; m < 2; ++m)
#pragma unroll
        for (int u = 0; u < 24; ++u)
            asm volatile("" : "+v"(wq[m][u].x), "+v"(wq[m][u].y),
                              "+v"(wq[m][u].z), "+v"(wq[m][u].w));

    // pairs 96..127 of both rows -> LDS (per-thread private 256B)
#pragma unroll
    for (int g = 0; g < 16; ++g)
        lds_wt[(g << 9) + tid] = wpackF[((48 + g) << 9) + tid];

    if (tid < 128) lds_h[tid] = 0u;    // h_{-1}=0 (pads 125..127 stay 0)
    float cc0 = 0.0f, cc1 = 0.0f;
    __syncthreads();

    float2 xg_cur = *(const float2*)&xg[row0];   // t = 0

#pragma unroll 1
    for (int t = 0; t < 4096; ++t) {
        const int tn = (t + 1 < 4096) ? t + 1 : 4095;
        float2 xg_nxt = *(const float2*)&xg[tn * 1000 + row0];

        float a0 = xg_cur.x, a1 = xg_cur.y;

        // phase A: pairs 0..95 from registers, h broadcast from LDS
#pragma unroll
        for (int J = 0; J < 6; ++J) {
            uint4 h0 = *(const uint4*)&lds_h[J * 16];
            uint4 h1 = *(const uint4*)&lds_h[J * 16 + 4];
            uint4 hx = *(const uint4*)&lds_h[J * 16 + 8];
            uint4 h3 = *(const uint4*)&lds_h[J * 16 + 12];
            DOT4(a0, wq[0][4 * J + 0], h0) DOT4(a0, wq[0][4 * J + 1], h1)
            DOT4(a0, wq[0][4 * J + 2], hx) DOT4(a0, wq[0][4 * J + 3], h3)
            DOT4(a1, wq[1][4 * J + 0], h0) DOT4(a1, wq[1][4 * J + 1], h1)
            DOT4(a1, wq[1][4 * J + 2], hx) DOT4(a1, wq[1][4 * J + 3], h3)
        }
        // phase B: pairs 96..127 streamed from LDS (zero-padded >=125)
#pragma unroll
        for (int c = 0; c < 8; ++c) {
            uint4 hh = *(const uint4*)&lds_h[96 + 4 * c];
            uint4 t0 = lds_wt[(c << 9) + tid];
            uint4 t1 = lds_wt[((8 + c) << 9) + tid];
            DOT4(a0, t0, hh)
            DOT4(a1, t1, hh)
        }

        // activation: sigmoid for i,f,o rows; tanh for g rows.
        {
            float e0 = __expf(isg ? 2.0f * a0 : -a0);
            float e1 = __expf(isg ? 2.0f * a1 : -a1);
            float s0 = __builtin_amdgcn_rcpf(1.0f + e0);
            float s1 = __builtin_amdgcn_rcpf(1.0f + e1);
            float v0 = isg ? fmaf(-2.0f, s0, 1.0f) : s0;
            float v1 = isg ? fmaf(-2.0f, s1, 1.0f) : s1;
            if (act_on) *(float2*)&lds_gates[2 * tid] = make_float2(v0, v1);
        }
        __syncthreads();   // gates ready; all lds_h reads of this step done

        if (tid < 125) {
            float2 gi = *(const float2*)&lds_gates[2 * tid];
            float2 gf = *(const float2*)&lds_gates[250 + 2 * tid];
            float2 gg = *(const float2*)&lds_gates[500 + 2 * tid];
            float2 go = *(const float2*)&lds_gates[750 + 2 * tid];
            cc0 = fmaf(gf.x, cc0, gi.x * gg.x);
            cc1 = fmaf(gf.y, cc1, gi.y * gg.y);
            float e0 = __expf(2.0f * cc0), e1 = __expf(2.0f * cc1);
            float t0 = fmaf(-2.0f, __builtin_amdgcn_rcpf(1.0f + e0), 1.0f);
            float t1 = fmaf(-2.0f, __builtin_amdgcn_rcpf(1.0f + e1), 1.0f);
            float h0 = go.x * t0;
            float h1 = go.y * t1;
            *(float2*)&hsf32[t * 250 + 2 * tid] = make_float2(h0, h1);
            h2 hp; hp[0] = (_Float16)h0; hp[1] = (_Float16)h1;
            lds_h[tid] = __builtin_bit_cast(unsigned, hp);
        }
        __syncthreads();   // h_t visible to all before next step's reads
        xg_cur = xg_nxt;
    }
}

// ---------------------------------------------------------------------------
// K4: logits = hs @ dense_w^T + dense_b; out = log_softmax rows.
// ---------------------------------------------------------------------------
__global__ __launch_bounds__(256) void dense_lsm(
    const float* __restrict__ hs, const float* __restrict__ dw,
    const float* __restrict__ db, float* __restrict__ out) {
    const int wave = threadIdx.x >> 6, lane = threadIdx.x & 63;
    const int s = blockIdx.x * 4 + wave;
    const int tag = lane;
    float acc = -1e30f;
    if (tag < 50) {
        acc = db[tag];
        const float* h = hs + (long)s * 250;
        const float* wrow = dw + tag * 250;
        for (int k = 0; k < 250; ++k) acc = fmaf(h[k], wrow[k], acc);
    }
    float m = acc;
#pragma unroll
    for (int off = 32; off; off >>= 1) m = fmaxf(m, __shfl_xor(m, off));
    float e = (tag < 50) ? expf(acc - m) : 0.0f;
    float ssum = e;
#pragma unroll
    for (int off = 32; off; off >>= 1) ssum += __shfl_xor(ssum, off);
    if (tag < 50) out[(long)s * 50 + tag] = acc - m - logf(ssum);
}

// ---------------------------------------------------------------------------
// launch. ws layout (21.5 MB; xT aliases hsf32 region — xT dead after K2):
//   [wpackF 524288][xg 16384000][hsf32/xT max(4096000, 4620288)]
// ---------------------------------------------------------------------------
extern "C" void kernel_launch(void* const* d_in, const int* in_sizes, int n_in,
                              void* d_out, int out_size, void* d_ws, size_t ws_size,
                              hipStream_t stream) {
    const int*   ci    = (const int*)d_in[0];
    const int*   wi    = (const int*)d_in[1];
    const float* cemb  = (const float*)d_in[2];
    const float* wemb  = (const float*)d_in[3];
    const float* convw = (const float*)d_in[4];
    const float* convb = (const float*)d_in[5];
    const float* wih   = (const float*)d_in[6];
    const float* whh   = (const float*)d_in[7];
    const float* bih   = (const float*)d_in[8];
    const float* bhh   = (const float*)d_in[9];
    const float* dw    = (const float*)d_in[10];
    const float* db    = (const float*)d_in[11];
    float* out = (float*)d_out;

    char* ws = (char*)d_ws;
    constexpr size_t OFF_WPF = 0;          // 524,288
    constexpr size_t OFF_XG  = 524288;     // 16,384,000
    constexpr size_t OFF_HSF = 16908288;   // 4,620,288 (shared with xT)
    constexpr size_t OFF_XT  = OFF_HSF;

    uint4* wpackF = (uint4*)(ws + OFF_WPF);
    float* xg     = (float*)(ws + OFF_XG);
    float* hsf32  = (float*)(ws + OFF_HSF);
    float* xT     = (float*)(ws + OFF_XT);

    prep_kernel<<<dim3(128), dim3(256), 0, stream>>>(whh, wpackF);
    build_xt<<<dim3(64), dim3(256), 0, stream>>>(ci, wi, cemb, wemb, convw,
                                                 convb, xT);
    xg_gemm<<<dim3(256, 4), dim3(256), 0, stream>>>(wih, xT, bih, bhh, xg);
    lstm_scan<<<dim3(1), dim3(512), 0, stream>>>(wpackF, xg, hsf32);
    dense_lsm<<<dim3(1024), dim3(256), 0, stream>>>(hsf32, dw, db, out);
}

// Round 7
// 13644.635 us; speedup vs baseline: 2.2378x; 2.2378x over previous
//
#include <hip/hip_runtime.h>
#include <hip/hip_bf16.h>
#include <hip/hip_fp16.h>

// ---------------------------------------------------------------------------
// POSTagger. Sizes: S=4096, LC=16, CDIM=10, F=32, WDIM=250, H=250, 4H=1000,
// K=F+WDIM=282, TAGS=50.
//
// LSTM (round 7): 10 blocks x 256 threads. Block b owns h-chunk
// j in [25b,25b+25) -> gate rows {j,250+j,500+j,750+j} (100 rows, 50KB f16
// weights: 8 uint4/thread in regs + 8 uint4/thread in LDS). Each block is
// self-sufficient for its cell update; h published via double-buffered global
// f16 slots; per-step agent-scope flag barrier (release fence + acquire poll).
// Rationale: single-CU is L2-BW-walled at ~512KB/step (r4 = 11.6ms) and the
// allocator caps VGPRs at 128 (r4/r6), so spread the weight stream across
// 10 CUs' LDS and pay one cross-CU barrier per step instead.
// ---------------------------------------------------------------------------

#define NBLK 10

typedef _Float16 h2 __attribute__((ext_vector_type(2)));

__device__ __forceinline__ float dot2(unsigned int w, unsigned int h, float acc) {
#if __has_builtin(__builtin_amdgcn_fdot2)
    return __builtin_amdgcn_fdot2(__builtin_bit_cast(h2, w),
                                  __builtin_bit_cast(h2, h), acc, false);
#else
    h2 a = __builtin_bit_cast(h2, w), b = __builtin_bit_cast(h2, h);
    return acc + (float)a[0] * (float)b[0] + (float)a[1] * (float)b[1];
#endif
}

// ---------------------------------------------------------------------------
// K0: pack W_hh (f16) for K3 + zero h-buffers and barrier flags.
// K3 thread (b,tid): r=tid>>1 (local row), half=tid&1 (k-half), valid tid<200.
// Global row grow = (r/25)*250 + 25b + (r%25). Thread covers h-pairs
// half*64 + [0..63] as 16 uint4 chunks cu (4 pairs each): cu<8 -> regs,
// cu>=8 -> LDS. wpackG[cu*2560 + b*256 + tid]; zero outside valid range.
// ---------------------------------------------------------------------------
__global__ void prep_kernel(const float* __restrict__ whh,  // [1000][250]
                            uint4* __restrict__ wpackG,
                            unsigned* __restrict__ hs16,    // [2][128] dwords
                            unsigned* __restrict__ done) {  // [NBLK]
    int id = blockIdx.x * 256 + threadIdx.x;
    if (id < 16 * 2560) {
        int cu = id / 2560, wslot = id % 2560;
        int tid = wslot & 255;
        int b = wslot >> 8;
        int r = tid >> 1, half = tid & 1;
        uint4 v = make_uint4(0u, 0u, 0u, 0u);
        if (tid < 200) {
            int grow = (r / 25) * 250 + 25 * b + (r % 25);
            int p0 = half * 64 + 4 * cu;
            unsigned ww[4];
#pragma unroll
            for (int c = 0; c < 4; ++c) {
                int p = p0 + c;
                float e0 = (2 * p < 250)     ? whh[grow * 250 + 2 * p]     : 0.0f;
                float e1 = (2 * p + 1 < 250) ? whh[grow * 250 + 2 * p + 1] : 0.0f;
                h2 hp; hp[0] = (_Float16)e0; hp[1] = (_Float16)e1;
                ww[c] = __builtin_bit_cast(unsigned, hp);
            }
            v.x = ww[0]; v.y = ww[1]; v.z = ww[2]; v.w = ww[3];
        }
        wpackG[id] = v;
        return;
    }
    int id2 = id - 16 * 2560;
    if (id2 < 256) { hs16[id2] = 0u; return; }       // both h buffers = 0
    int id3 = id2 - 256;
    if (id3 < NBLK) done[id3] = 0u;                  // barrier flags = 0
}

// ---------------------------------------------------------------------------
// K1: xT[282][4096]: rows 0..31 = char-CNN features^T (conv3 pad1 + bias +
// max over time), rows 32..281 = word embeddings^T. 64 words/block.
// ---------------------------------------------------------------------------
__global__ __launch_bounds__(256) void build_xt(
    const int* __restrict__ ci, const int* __restrict__ wi,
    const float* __restrict__ cemb, const float* __restrict__ wemb,
    const float* __restrict__ convw, const float* __restrict__ convb,
    float* __restrict__ xT) {
    __shared__ float ce[64][16][10];
    __shared__ float cw[32][30];
    __shared__ float cb[32];
    __shared__ int widx[64];
    const int tid = threadIdx.x;
    const int w0 = blockIdx.x * 64;

    for (int i = tid; i < 960; i += 256) cw[i / 30][i % 30] = convw[i];
    if (tid < 32) cb[tid] = convb[tid];
    if (tid < 64) widx[tid] = wi[w0 + tid];
    for (int i = tid; i < 1024; i += 256) {
        int w = i >> 4, lc = i & 15;
        int idx = ci[(w0 + w) * 16 + lc];
#pragma unroll
        for (int c = 0; c < 10; ++c) ce[w][lc][c] = cemb[idx * 10 + c];
    }
    __syncthreads();

    for (int i = tid; i < 2048; i += 256) {
        int w = i >> 5, f = i & 31;
        float mx = -1e30f;
        for (int t = 0; t < 16; ++t) {
            float s = cb[f];
#pragma unroll
            for (int dt = 0; dt < 3; ++dt) {
                int tt = t + dt - 1;
                if (tt >= 0 && tt < 16) {
#pragma unroll
                    for (int c = 0; c < 10; ++c)
                        s += ce[w][tt][c] * cw[f][c * 3 + dt];
                }
            }
            mx = fmaxf(mx, s);
        }
        xT[f * 4096 + w0 + w] = mx;
    }
    for (int i = tid; i < 64 * 250; i += 256) {
        int w = i & 63, jj = i >> 6;
        xT[(32 + jj) * 4096 + w0 + w] = wemb[(long)widx[w] * 250 + jj];
    }
}

// ---------------------------------------------------------------------------
// K2: xg[4096][1000] = x @ W_ih^T + (b_ih + b_hh).
// ---------------------------------------------------------------------------
__global__ __launch_bounds__(256) void xg_gemm(
    const float* __restrict__ wih,  // [1000][282]
    const float* __restrict__ xT,   // [282][4096]
    const float* __restrict__ bih, const float* __restrict__ bhh,
    float* __restrict__ xg) {       // [4096][1000]
    const int g = blockIdx.y * 256 + threadIdx.x;
    const int gg = (g < 1000) ? g : 999;
    const int w0 = blockIdx.x * 16;
    float acc[16];
#pragma unroll
    for (int i = 0; i < 16; ++i) acc[i] = 0.0f;
    const float* wrow = wih + gg * 282;
    for (int k = 0; k < 282; ++k) {
        float wv = wrow[k];
        const float* xrow = xT + k * 4096 + w0;
#pragma unroll
        for (int i = 0; i < 16; ++i) acc[i] = fmaf(wv, xrow[i], acc[i]);
    }
    if (g < 1000) {
        float b = bih[g] + bhh[g];
#pragma unroll
        for (int i = 0; i < 16; ++i) xg[(w0 + i) * 1000 + g] = acc[i] + b;
    }
}

// ---------------------------------------------------------------------------
// K3: sequential LSTM across 10 CUs with a per-step flag barrier.
// Gate rows: i=0..249, f=250..499, g=500..749 (tanh), o=750..999.
// ---------------------------------------------------------------------------
#define DOT4(ACC, W, H)                                                     \
    ACC = dot2((W).x, (H).x, ACC); ACC = dot2((W).y, (H).y, ACC);           \
    ACC = dot2((W).z, (H).z, ACC); ACC = dot2((W).w, (H).w, ACC);

__global__ __launch_bounds__(256) void lstm_scan(
    const uint4* __restrict__ wpackG,  // [16][NBLK*256]
    const float* __restrict__ xg,      // [4096][1000]
    unsigned* __restrict__ hs16,       // [2][128] f16-pair dwords
    unsigned* __restrict__ done,       // [NBLK]
    float* __restrict__ hsf32) {       // [4096][250]
    __shared__ uint4 lds_w[256 * 8];   // 32 KB, rotated chunks 8..15
    __shared__ float lds_gates[100];

    const int b = blockIdx.x;
    const int tid = threadIdx.x;
    const int r = tid >> 1, half = tid & 1;
    const bool comp = (tid < 200);
    const int gate = r / 25;
    const int grow = comp ? gate * 250 + 25 * b + (r % 25) : 0;
    const bool isg = comp && (gate == 2);
    const int wslot = (b << 8) + tid;

    // chunks 0..7 -> 8 uint4 = 32 VGPRs (fits the 128-reg budget easily)
    uint4 wq[8];
#pragma unroll
    for (int u = 0; u < 8; ++u) wq[u] = wpackG[u * 2560 + wslot];
    // chunks 8..15 -> LDS, rotated so per-step reads sit at the b128 BW floor
#pragma unroll
    for (int u = 0; u < 8; ++u)
        lds_w[(tid << 3) | ((u + tid) & 7)] = wpackG[(8 + u) * 2560 + wslot];

    float cc = 0.0f;                 // cell state (threads tid<25)
    __syncthreads();

    float xg_cur = xg[grow];         // t = 0 (clamped row for tid>=200)

#pragma unroll 1
    for (int t = 0; t < 4096; ++t) {
        const int tn = (t + 1 < 4096) ? t + 1 : 4095;
        float xg_nxt = xg[tn * 1000 + grow];

        // h_{t-1}: this thread's 64 pair-dwords of buffer t&1
        const unsigned* hb = hs16 + ((t & 1) << 7) + (half << 6);
        uint4 ha[8], hc[8];
#pragma unroll
        for (int c = 0; c < 8; ++c) ha[c] = *(const uint4*)(hb + 4 * c);
#pragma unroll
        for (int c = 0; c < 8; ++c) hc[c] = *(const uint4*)(hb + 32 + 4 * c);

        float acc = 0.0f;
#pragma unroll
        for (int c = 0; c < 8; ++c) { DOT4(acc, wq[c], ha[c]) }
#pragma unroll
        for (int c = 0; c < 8; ++c) {
            uint4 w = lds_w[(tid << 3) | ((c + tid) & 7)];
            DOT4(acc, w, hc[c])
        }

        float tot = acc + __shfl_xor(acc, 1);   // combine k-halves
        if (comp && half == 0) {
            float a = tot + xg_cur;
            float e = __expf(isg ? 2.0f * a : -a);
            float s = __builtin_amdgcn_rcpf(1.0f + e);
            lds_gates[r] = isg ? fmaf(-2.0f, s, 1.0f) : s;
        }
        __syncthreads();                         // gates visible in-block

        if (tid < 25) {
            float gi = lds_gates[tid];
            float gf = lds_gates[25 + tid];
            float gg = lds_gates[50 + tid];
            float go = lds_gates[75 + tid];
            cc = fmaf(gf, cc, gi * gg);
            float e = __expf(2.0f * cc);
            float th = fmaf(-2.0f, __builtin_amdgcn_rcpf(1.0f + e), 1.0f);
            float h = go * th;
            int jg = 25 * b + tid;
            hsf32[t * 250 + jg] = h;
            _Float16* hw = (_Float16*)(hs16 + (((t + 1) & 1) << 7));
            hw[jg] = (_Float16)h;
            // make h stores visible agent-wide before the flag
            __builtin_amdgcn_fence(__ATOMIC_RELEASE, "agent");
        }
        if (tid == 0)
            __hip_atomic_store(&done[b], (unsigned)(t + 1), __ATOMIC_RELAXED,
                               __HIP_MEMORY_SCOPE_AGENT);
        if (tid < NBLK) {
            while (__hip_atomic_load(&done[tid], __ATOMIC_ACQUIRE,
                                     __HIP_MEMORY_SCOPE_AGENT) <
                   (unsigned)(t + 1)) { }
        }
        __syncthreads();                         // all pollers done
        // per-wave acquire: invalidate caches before next step's h loads
        __builtin_amdgcn_fence(__ATOMIC_ACQUIRE, "agent");
        xg_cur = xg_nxt;
    }
}

// ---------------------------------------------------------------------------
// K4: logits = hs @ dense_w^T + dense_b; out = log_softmax rows.
// ---------------------------------------------------------------------------
__global__ __launch_bounds__(256) void dense_lsm(
    const float* __restrict__ hs, const float* __restrict__ dw,
    const float* __restrict__ db, float* __restrict__ out) {
    const int wave = threadIdx.x >> 6, lane = threadIdx.x & 63;
    const int s = blockIdx.x * 4 + wave;
    const int tag = lane;
    float acc = -1e30f;
    if (tag < 50) {
        acc = db[tag];
        const float* h = hs + (long)s * 250;
        const float* wrow = dw + tag * 250;
        for (int k = 0; k < 250; ++k) acc = fmaf(h[k], wrow[k], acc);
    }
    float m = acc;
#pragma unroll
    for (int off = 32; off; off >>= 1) m = fmaxf(m, __shfl_xor(m, off));
    float e = (tag < 50) ? expf(acc - m) : 0.0f;
    float ssum = e;
#pragma unroll
    for (int off = 32; off; off >>= 1) ssum += __shfl_xor(ssum, off);
    if (tag < 50) out[(long)s * 50 + tag] = acc - m - logf(ssum);
}

// ---------------------------------------------------------------------------
// launch. ws (~22.2 MB): [wpackG 655360][xg 16384000][hs16 1024][done 1024]
// [hsf32 4096000 + 524288 tail pad; xT (4,620,288) aliases hsf32 span —
// xT dead after K2, and hs16/done live BEFORE the aliased region].
// ---------------------------------------------------------------------------
extern "C" void kernel_launch(void* const* d_in, const int* in_sizes, int n_in,
                              void* d_out, int out_size, void* d_ws, size_t ws_size,
                              hipStream_t stream) {
    const int*   ci    = (const int*)d_in[0];
    const int*   wi    = (const int*)d_in[1];
    const float* cemb  = (const float*)d_in[2];
    const float* wemb  = (const float*)d_in[3];
    const float* convw = (const float*)d_in[4];
    const float* convb = (const float*)d_in[5];
    const float* wih   = (const float*)d_in[6];
    const float* whh   = (const float*)d_in[7];
    const float* bih   = (const float*)d_in[8];
    const float* bhh   = (const float*)d_in[9];
    const float* dw    = (const float*)d_in[10];
    const float* db    = (const float*)d_in[11];
    float* out = (float*)d_out;

    char* ws = (char*)d_ws;
    constexpr size_t OFF_WPG  = 0;           // 655,360
    constexpr size_t OFF_XG   = 655360;      // 16,384,000
    constexpr size_t OFF_HS16 = 17039360;    // 1,024
    constexpr size_t OFF_DONE = 17040384;    // 1,024
    constexpr size_t OFF_HSF  = 17041408;    // 4,620,288 span (hsf32 + xT alias)
    constexpr size_t OFF_XT   = OFF_HSF;

    uint4*    wpackG = (uint4*)(ws + OFF_WPG);
    float*    xg     = (float*)(ws + OFF_XG);
    unsigned* hs16   = (unsigned*)(ws + OFF_HS16);
    unsigned* done   = (unsigned*)(ws + OFF_DONE);
    float*    hsf32  = (float*)(ws + OFF_HSF);
    float*    xT     = (float*)(ws + OFF_XT);

    prep_kernel<<<dim3(162), dim3(256), 0, stream>>>(whh, wpackG, hs16, done);
    build_xt<<<dim3(64), dim3(256), 0, stream>>>(ci, wi, cemb, wemb, convw,
                                                 convb, xT);
    xg_gemm<<<dim3(256, 4), dim3(256), 0, stream>>>(wih, xT, bih, bhh, xg);
    lstm_scan<<<dim3(NBLK), dim3(256), 0, stream>>>(wpackG, xg, hs16, done,
                                                    hsf32);
    dense_lsm<<<dim3(1024), dim3(256), 0, stream>>>(hsf32, dw, db, out);
}